// Round 16
// baseline (1616.800 us; speedup 1.0000x reference)
//
#include <hip/hip_runtime.h>
#include <stdint.h>

#define NB   16
#define CIN  512
#define COUT 512
#define HH   64
#define WW   64
#define NCOND 512
#define TAPS 9
#define EPSD 1e-8f

typedef short bf16x8 __attribute__((ext_vector_type(8)));
typedef float f32x4 __attribute__((ext_vector_type(4)));

static __device__ __forceinline__ short f2bf(float f) {
  union { float f; uint32_t u; } c;
  c.f = f;
  uint32_t u = c.u;
  uint32_t r = (u + 0x7FFFu + ((u >> 16) & 1u)) >> 16;
  return (short)(uint16_t)r;
}

static __device__ __forceinline__ void gl_lds16(const void* g, void* l) {
  __builtin_amdgcn_global_load_lds(
      (const __attribute__((address_space(1))) void*)g,
      (__attribute__((address_space(3))) void*)l, 16, 0, 0);
}

// ---- k_pg: fused {prep2 (blocks 0..511)} + {gamma (blocks 512..527)} --------
__global__ __launch_bounds__(512) void k_pg(const float* __restrict__ w_conv,
                                            const float* __restrict__ y,
                                            const float* __restrict__ w_gamma,
                                            const float* __restrict__ b_gamma,
                                            float* __restrict__ s2,
                                            short* __restrict__ W2,
                                            float* __restrict__ gamma,
                                            float* __restrict__ zbuf) {
  __shared__ float ws_s[CIN * TAPS];
  const int t = threadIdx.x;
  if (blockIdx.x < 512) {
    const int o = blockIdx.x;
    const float* wsrc = w_conv + (size_t)o * CIN * TAPS;
    for (int idx = t; idx < CIN * TAPS; idx += 512) ws_s[idx] = wsrc[idx];
    __syncthreads();
    {
      int i = t;
      float s = 0.f;
#pragma unroll
      for (int tap = 0; tap < TAPS; ++tap) {
        float v = ws_s[i * TAPS + tap];
        s += v * v;
      }
      s2[(size_t)o * CIN + i] = s;
    }
    const int key = (o >> 1) & 3;
    for (int k = t; k < CIN * TAPS; k += 512) {
      int tap = k >> 9;
      int r = k & 511;
      int c = r >> 5, sl = (r >> 3) & 3, j = r & 7;
      W2[((size_t)(c * TAPS + tap) * COUT + o) * 32 + ((sl ^ key) * 8) + j] =
          f2bf(ws_s[r * TAPS + tap]);
    }
  } else {
    const int b = blockIdx.x - 512;
    if (b == 0) { zbuf[t] = 0.f; zbuf[t + 512] = 0.f; }
    ws_s[t] = y[b * NCOND + t];
    __syncthreads();
    const float4* wg = reinterpret_cast<const float4*>(w_gamma + (size_t)t * NCOND);
    float acc = b_gamma[t];
    for (int c4 = 0; c4 < NCOND / 4; ++c4) {
      float4 w4 = wg[c4];
      acc += w4.x * ws_s[c4 * 4 + 0] + w4.y * ws_s[c4 * 4 + 1] +
             w4.z * ws_s[c4 * 4 + 2] + w4.w * ws_s[c4 * 4 + 3];
    }
    gamma[b * CIN + t] = acc;
  }
}

// ---------------- k_d3: parallel demod scale (grid 128) ----------------------
__global__ __launch_bounds__(512) void k_d3(const float* __restrict__ gamma,
                                            const float* __restrict__ s2,
                                            float* __restrict__ dscale) {
  __shared__ float g2[CIN];
  __shared__ float red[512];
  const int b = blockIdx.x >> 3;
  const int og = blockIdx.x & 7;
  const int t = threadIdx.x;
  float g = gamma[b * CIN + t];
  g2[t] = g * g;
  __syncthreads();
  const int o_l = t >> 3, seg = t & 7;
  const int o = og * 64 + o_l;
  const float4* s4 = reinterpret_cast<const float4*>(s2 + (size_t)o * CIN + seg * 64);
  float p = 0.f;
#pragma unroll
  for (int c4 = 0; c4 < 16; ++c4) {
    float4 v = s4[c4];
    int base = seg * 64 + c4 * 4;
    p += v.x * g2[base + 0] + v.y * g2[base + 1] +
         v.z * g2[base + 2] + v.w * g2[base + 3];
  }
  red[t] = p;
  __syncthreads();
  if (seg == 0) {
    float s = 0.f;
#pragma unroll
    for (int k = 0; k < 8; ++k) s += red[o_l * 8 + k];
    dscale[b * COUT + o] = rsqrtf(s + EPSD);
  }
}

// ---------------- fallback prelude kernels -----------------------------------
__global__ __launch_bounds__(512) void k_gamma(const float* __restrict__ y,
                                               const float* __restrict__ w_gamma,
                                               const float* __restrict__ b_gamma,
                                               float* __restrict__ gamma,
                                               float* __restrict__ zbuf) {
  __shared__ float ys[NCOND];
  const int b = blockIdx.x;
  const int i = threadIdx.x;
  if (zbuf && b == 0) { zbuf[i] = 0.f; zbuf[i + 512] = 0.f; }
  ys[i] = y[b * NCOND + i];
  __syncthreads();
  const float4* wg = reinterpret_cast<const float4*>(w_gamma + (size_t)i * NCOND);
  float acc = b_gamma[i];
  for (int c4 = 0; c4 < NCOND / 4; ++c4) {
    float4 w4 = wg[c4];
    acc += w4.x * ys[c4 * 4 + 0] + w4.y * ys[c4 * 4 + 1] +
           w4.z * ys[c4 * 4 + 2] + w4.w * ys[c4 * 4 + 3];
  }
  gamma[b * CIN + i] = acc;
}

__global__ __launch_bounds__(256) void k_prep(const float* __restrict__ w_conv,
                                              float* __restrict__ s2,
                                              short* __restrict__ Wr) {
  __shared__ float ws_s[CIN * TAPS];
  const int o = blockIdx.x;
  const int t = threadIdx.x;
  const float* wsrc = w_conv + (size_t)o * CIN * TAPS;
  for (int idx = t; idx < CIN * TAPS; idx += 256) ws_s[idx] = wsrc[idx];
  __syncthreads();
  for (int i = t; i < CIN; i += 256) {
    float s = 0.f;
#pragma unroll
    for (int tap = 0; tap < TAPS; ++tap) {
      float v = ws_s[i * TAPS + tap];
      s += v * v;
    }
    s2[(size_t)o * CIN + i] = s;
  }
  for (int idx = t; idx < CIN * TAPS; idx += 256) {
    int i = idx & (CIN - 1);
    int tap = idx >> 9;
    Wr[((size_t)o * TAPS + tap) * CIN + i] = f2bf(ws_s[i * TAPS + tap]);
  }
}

__global__ __launch_bounds__(512) void k_d(const float* __restrict__ gamma,
                                           const float* __restrict__ s2,
                                           float* __restrict__ dscale) {
  __shared__ float g2[CIN];
  const int b = blockIdx.x;
  const int o = threadIdx.x;
  float g = gamma[b * CIN + o];
  g2[o] = g * g;
  __syncthreads();
  const float4* s4 = reinterpret_cast<const float4*>(s2 + (size_t)o * CIN);
  float acc = 0.f;
  for (int i4 = 0; i4 < CIN / 4; ++i4) {
    float4 v = s4[i4];
    acc += v.x * g2[i4 * 4 + 0] + v.y * g2[i4 * 4 + 1] +
           v.z * g2[i4 * 4 + 2] + v.w * g2[i4 * 4 + 3];
  }
  dscale[b * COUT + o] = rsqrtf(acc + EPSD);
}

// -- k_xmod2: xm[b][y][w][cin] bf16 modulated, 16B-slot pre-swizzled by w -----
__global__ __launch_bounds__(256) void k_xmod2(const float* __restrict__ x,
                                               const float* __restrict__ gamma,
                                               short* __restrict__ xm) {
  __shared__ float tile[64][67];
  __shared__ float gs[CIN];
  const int y = blockIdx.x, b = blockIdx.y;
  const int t = threadIdx.x;
  gs[t] = gamma[b * CIN + t];
  gs[t + 256] = gamma[b * CIN + t + 256];
  __syncthreads();
  const int w = t >> 2, q = t & 3;
  const int sw = (w >> 1) & 3;
  short* dst = xm + (((size_t)b * HH + y) * WW + w) * CIN;
  for (int c0 = 0; c0 < CIN; c0 += 64) {
    {
      int ww_ = t & 63;
      int cb = t >> 6;
      const float* xp = x + (((size_t)(b * CIN + c0 + cb)) * HH + y) * WW + ww_;
#pragma unroll
      for (int p = 0; p < 16; ++p)
        tile[cb + p * 4][ww_] = xp[(size_t)p * 4 * HH * WW];
    }
    __syncthreads();
#pragma unroll
    for (int h = 0; h < 2; ++h) {
      int c_lo = q * 16 + h * 8;
      int chunk = (c0 + c_lo) >> 5;
      int sl = (c_lo >> 3) & 3;
      short tmp[8];
#pragma unroll
      for (int j = 0; j < 8; ++j)
        tmp[j] = f2bf(tile[c_lo + j][w] * gs[c0 + c_lo + j]);
      *reinterpret_cast<bf16x8*>(dst + chunk * 32 + (sl ^ sw) * 8) =
          *reinterpret_cast<const bf16x8*>(tmp);
    }
    __syncthreads();
  }
}

// ---------------- k_conv13 (unchanged, verified): B-pipelined conv -----------
__global__ __launch_bounds__(256, 2) void k_conv13(const short* __restrict__ xm,
                                                   const short* __restrict__ W2,
                                                   const short* __restrict__ zbuf,
                                                   const float* __restrict__ dscale,
                                                   float* __restrict__ out) {
  __shared__ short Xs[2 * 6 * 64 * 32];
  __shared__ float d_s[128];
  __shared__ __align__(16) short zls[64];

  const int orig = blockIdx.x;
  const int wgid = ((orig & 7) << 7) | (orig >> 3);
  const int ot = wgid >> 8;
  const int b  = (wgid >> 4) & 15;
  const int sp = wgid & 15;

  const int t = threadIdx.x, lane = t & 63;
  const int wc = t >> 6;
  const int l15 = lane & 15;
  const int slA = lane >> 4;

  if (t < 128) d_s[t] = dscale[b * COUT + ot * 128 + t];
  if (t < 64) zls[t] = 0;

  const short* xS[6];
#pragma unroll
  for (int i = 0; i < 6; ++i) {
    int idx = t + 256 * i;
    int rb = idx >> 8;
    int w = (idx & 255) >> 2;
    int sl = idx & 3;
    int ysrc = sp * 4 + rb - 1;
    bool rv = (ysrc >= 0) && (ysrc < HH);
    xS[i] = rv ? xm + (((size_t)b * HH + ysrc) * WW + w) * CIN + sl * 8
               : zbuf + sl * 8;
  }

  const int o0 = ot * 128 + l15;
  const int keyA = (o0 >> 1) & 3;
  const short* aGc = W2 + (size_t)o0 * 32 + ((slA ^ keyA) * 8);

  const int kb0 = slA << 4;
  const char* pbx[3];
#pragma unroll
  for (int dxi = 0; dxi < 3; ++dxi) {
    int lcc = l15 + dxi - 1;
    int key = (lcc >> 1) & 3;
    pbx[dxi] = (const char*)&Xs[0] + lcc * 64 + (kb0 ^ (key << 4));
  }
  const int lc3 = (l15 + 1 > 15) ? 15 : (l15 + 1);
  const char* pbx3 = (const char*)&Xs[0] + lc3 * 64 + (kb0 ^ (((lc3 >> 1) & 3) << 4));
  char* wx0 = (char*)&Xs[0] + t * 16;
  const char* zl = (const char*)&zls[0];
  const bool mL = (l15 == 0);
  const bool mR = (l15 == 15);

  f32x4 acc[8][4];
#pragma unroll
  for (int m = 0; m < 8; ++m)
#pragma unroll
    for (int n = 0; n < 4; ++n)
      acc[m][n] = (f32x4){0.f, 0.f, 0.f, 0.f};

  bf16x8 aA[8], aB[8];
  bf16x8 bS[3];

#pragma unroll
  for (int i = 0; i < 6; ++i)
    gl_lds16(xS[i], wx0 + i * 4096);
#pragma unroll
  for (int m = 0; m < 8; ++m)
    aA[m] = *reinterpret_cast<const bf16x8*>(aGc + m * 512);
  asm volatile("s_waitcnt vmcnt(0) lgkmcnt(0)" ::: "memory");
  __builtin_amdgcn_s_barrier();
  asm volatile("" ::: "memory");

#define LD8(p) (*reinterpret_cast<const bf16x8*>(p))

#define ADDR_B(tq_, nq_)                                                      \
  ({ const int dyz_ = (tq_) / 3 - 1, dxz_ = (tq_) % 3 - 1;                    \
     const int rboz_ = (wc + dyz_ + 1) * 4096;                                \
     const char* pz_;                                                         \
     if (dxz_ == -1 && (nq_) == 0) pz_ = mL ? (zl - rboz_) : qq0;             \
     else if (dxz_ == 1 && (nq_) == 3) pz_ = mR ? (zl - rboz_ - 3072) : qq3;  \
     else pz_ = (dxz_ == -1) ? qq0 : ((dxz_ == 0) ? qq1 : qq2);               \
     pz_ + rboz_ + (nq_) * 1024; })

#define DO_TAP(tp, CUR, NXT, NXTOFF, STGX, KNV)                               \
  {                                                                           \
    const short* an_ = aGc + (NXTOFF);                                        \
    _Pragma("unroll") for (int m_ = 0; m_ < 8; ++m_)                          \
        NXT[m_] = LD8(an_ + m_ * 512);                                        \
    if (STGX) {                                                               \
      _Pragma("unroll") for (int i_ = 0; i_ < 6; ++i_)                        \
          gl_lds16(xS[i_] + (KNV), wxw + i_ * 4096);                          \
    }                                                                         \
    _Pragma("unroll") for (int n_ = 0; n_ < 4; ++n_) {                        \
      const int j_ = (tp) * 4 + n_;                                           \
      if (j_ <= 33) { asm volatile("s_waitcnt lgkmcnt(2)" ::: "memory"); }    \
      else if (j_ == 34) { asm volatile("s_waitcnt lgkmcnt(1)" ::: "memory"); } \
      else { asm volatile("s_waitcnt lgkmcnt(0)" ::: "memory"); }             \
      __builtin_amdgcn_sched_barrier(0);                                      \
      __builtin_amdgcn_s_setprio(1);                                          \
      _Pragma("unroll") for (int m_ = 0; m_ < 8; ++m_)                        \
        acc[m_][n_] = __builtin_amdgcn_mfma_f32_16x16x32_bf16(                \
            CUR[m_], bS[j_ % 3], acc[m_][n_], 0, 0, 0);                       \
      __builtin_amdgcn_s_setprio(0);                                          \
      if (j_ + 3 <= 35) {                                                     \
        const int jn_ = j_ + 3, tr_ = jn_ >> 2, nr_ = jn_ & 3;                \
        bS[jn_ % 3] = LD8(ADDR_B(tr_, nr_));                                  \
      }                                                                       \
    }                                                                         \
  }

#define CHUNK_TAPS(A0, A1, NX8, KNV)                                          \
  bS[0] = LD8(ADDR_B(0, 0));                                                  \
  bS[1] = LD8(ADDR_B(0, 1));                                                  \
  bS[2] = LD8(ADDR_B(0, 2));                                                  \
  DO_TAP(0, A0, A1, 16384, false, 0)                                          \
  DO_TAP(1, A1, A0, 32768, false, 0)                                          \
  DO_TAP(2, A0, A1, 49152, false, 0)                                          \
  DO_TAP(3, A1, A0, 65536, false, 0)                                          \
  DO_TAP(4, A0, A1, 81920, false, 0)                                          \
  DO_TAP(5, A1, A0, 98304, false, 0)                                          \
  DO_TAP(6, A0, A1, 114688, false, 0)                                         \
  DO_TAP(7, A1, A0, 131072, true, KNV)                                        \
  DO_TAP(8, A0, A1, (NX8), false, 0)                                          \
  __builtin_amdgcn_sched_barrier(0);                                          \
  asm volatile("s_waitcnt vmcnt(8)" ::: "memory");                            \
  __builtin_amdgcn_s_barrier();                                               \
  asm volatile("" ::: "memory");

  for (int c2 = 0; c2 < 8; ++c2) {
    {
      const char* qq0 = pbx[0];
      const char* qq1 = pbx[1];
      const char* qq2 = pbx[2];
      const char* qq3 = pbx3;
      char* wxw = wx0 + 24576;
      const int knv = (2 * c2 + 1) * 32;
      CHUNK_TAPS(aA, aB, 147456, knv)
    }
    aGc += 147456;
    {
      const char* qq0 = pbx[0] + 24576;
      const char* qq1 = pbx[1] + 24576;
      const char* qq2 = pbx[2] + 24576;
      const char* qq3 = pbx3 + 24576;
      char* wxw = wx0;
      const int knv = (c2 < 7) ? (2 * c2 + 2) * 32 : 0;
      const int nx8 = (c2 < 7) ? 147456 : 0;
      CHUNK_TAPS(aB, aA, nx8, knv)
    }
    aGc += 147456;
  }
#undef CHUNK_TAPS
#undef DO_TAP
#undef ADDR_B
#undef LD8

#pragma unroll
  for (int m = 0; m < 8; ++m) {
#pragma unroll
    for (int n = 0; n < 4; ++n) {
#pragma unroll
      for (int j = 0; j < 4; ++j) {
        int o_l = m * 16 + (lane >> 4) * 4 + j;
        int o = ot * 128 + o_l;
        int yy = sp * 4 + wc;
        int cx = n * 16 + l15;
        out[(((size_t)b * COUT + o) * HH + yy) * WW + cx] = d_s[o_l] * acc[m][n][j];
      }
    }
  }
}

// ---------------- k_probeM: MFMA-only floor probe (2x conv FLOPs) ------------
// grid 2048, 256 thr, 2 blocks/CU. Same 32-MFMA/tap clusters + setprio as
// conv13, zero memory traffic. If issue is clean: ~300us @ ~95% MfmaUtil.
__global__ __launch_bounds__(256, 2) void k_probeM(const float* __restrict__ dscale,
                                                   float* __restrict__ sink) {
  const int t = threadIdx.x;
  f32x4 acc[8][4];
#pragma unroll
  for (int m = 0; m < 8; ++m)
#pragma unroll
    for (int n = 0; n < 4; ++n)
      acc[m][n] = (f32x4){0.f, 0.f, 0.f, 0.f};
  bf16x8 aF[8], bF[4];
  const bf16x8* src = reinterpret_cast<const bf16x8*>(dscale);
#pragma unroll
  for (int m = 0; m < 8; ++m) aF[m] = src[(t + m * 37) & 1023];
#pragma unroll
  for (int n = 0; n < 4; ++n) bF[n] = src[(t * 3 + n * 11) & 1023];
  for (int s = 0; s < 144; ++s) {
#pragma unroll
    for (int n = 0; n < 4; ++n) {
      __builtin_amdgcn_s_setprio(1);
#pragma unroll
      for (int m = 0; m < 8; ++m)
        acc[m][n] = __builtin_amdgcn_mfma_f32_16x16x32_bf16(aF[m], bF[n],
                                                            acc[m][n], 0, 0, 0);
      __builtin_amdgcn_s_setprio(0);
    }
  }
  float r = 0.f;
#pragma unroll
  for (int m = 0; m < 8; ++m)
#pragma unroll
    for (int n = 0; n < 4; ++n)
#pragma unroll
      for (int j = 0; j < 4; ++j) r += acc[m][n][j];
  sink[((blockIdx.x & 511) << 8) | t] = r;
}

// ---------------- k_probeL: memory-path probe (3x conv path, no MFMA) --------
// conv13's full load/stage/barrier/wait skeleton; frags consumed by 1-element
// XOR at the MFMA sites (keeps loads live + latency exposure identical).
__global__ __launch_bounds__(256, 2) void k_probeL(const short* __restrict__ xm,
                                                   const short* __restrict__ W2,
                                                   const short* __restrict__ zbuf,
                                                   const float* __restrict__ dscale,
                                                   float* __restrict__ sink) {
  __shared__ short Xs[2 * 6 * 64 * 32];
  __shared__ float d_s[128];
  __shared__ __align__(16) short zls[64];

  const int orig = blockIdx.x;
  const int wgid = ((orig & 7) << 7) | (orig >> 3);
  const int ot = wgid >> 8;
  const int b  = (wgid >> 4) & 15;
  const int sp = wgid & 15;

  const int t = threadIdx.x, lane = t & 63;
  const int wc = t >> 6;
  const int l15 = lane & 15;
  const int slA = lane >> 4;

  if (t < 128) d_s[t] = dscale[b * COUT + ot * 128 + t];
  if (t < 64) zls[t] = 0;

  const short* xS[6];
#pragma unroll
  for (int i = 0; i < 6; ++i) {
    int idx = t + 256 * i;
    int rb = idx >> 8;
    int w = (idx & 255) >> 2;
    int sl = idx & 3;
    int ysrc = sp * 4 + rb - 1;
    bool rv = (ysrc >= 0) && (ysrc < HH);
    xS[i] = rv ? xm + (((size_t)b * HH + ysrc) * WW + w) * CIN + sl * 8
               : zbuf + sl * 8;
  }

  const int o0 = ot * 128 + l15;
  const int keyA = (o0 >> 1) & 3;
  const short* aG0 = W2 + (size_t)o0 * 32 + ((slA ^ keyA) * 8);

  const int kb0 = slA << 4;
  const char* pbx[3];
#pragma unroll
  for (int dxi = 0; dxi < 3; ++dxi) {
    int lcc = l15 + dxi - 1;
    int key = (lcc >> 1) & 3;
    pbx[dxi] = (const char*)&Xs[0] + lcc * 64 + (kb0 ^ (key << 4));
  }
  const int lc3 = (l15 + 1 > 15) ? 15 : (l15 + 1);
  const char* pbx3 = (const char*)&Xs[0] + lc3 * 64 + (kb0 ^ (((lc3 >> 1) & 3) << 4));
  char* wx0 = (char*)&Xs[0] + t * 16;
  const char* zl = (const char*)&zls[0];
  const bool mL = (l15 == 0);
  const bool mR = (l15 == 15);

  bf16x8 aA[8], aB[8];
  bf16x8 bS[3];
  unsigned short snk = (unsigned short)t;

#define LD8(p) (*reinterpret_cast<const bf16x8*>(p))

#define P_ADDR_B(tq_, nq_)                                                    \
  ({ const int dyz_ = (tq_) / 3 - 1, dxz_ = (tq_) % 3 - 1;                    \
     const int rboz_ = (wc + dyz_ + 1) * 4096;                                \
     const char* pz_;                                                         \
     if (dxz_ == -1 && (nq_) == 0) pz_ = mL ? (zl - rboz_) : qq0;             \
     else if (dxz_ == 1 && (nq_) == 3) pz_ = mR ? (zl - rboz_ - 3072) : qq3;  \
     else pz_ = (dxz_ == -1) ? qq0 : ((dxz_ == 0) ? qq1 : qq2);               \
     pz_ + rboz_ + (nq_) * 1024; })

#define P_DO_TAP(tp, CUR, NXT, NXTOFF, STGX, KNV)                             \
  {                                                                           \
    const short* an_ = aGc + (NXTOFF);                                        \
    _Pragma("unroll") for (int m_ = 0; m_ < 8; ++m_)                          \
        NXT[m_] = LD8(an_ + m_ * 512);                                        \
    if (STGX) {                                                               \
      _Pragma("unroll") for (int i_ = 0; i_ < 6; ++i_)                        \
          gl_lds16(xS[i_] + (KNV), wxw + i_ * 4096);                          \
    }                                                                         \
    _Pragma("unroll") for (int n_ = 0; n_ < 4; ++n_) {                        \
      const int j_ = (tp) * 4 + n_;                                           \
      if (j_ <= 33) { asm volatile("s_waitcnt lgkmcnt(2)" ::: "memory"); }    \
      else if (j_ == 34) { asm volatile("s_waitcnt lgkmcnt(1)" ::: "memory"); } \
      else { asm volatile("s_waitcnt lgkmcnt(0)" ::: "memory"); }             \
      __builtin_amdgcn_sched_barrier(0);                                      \
      snk ^= (unsigned short)bS[j_ % 3][0];                                   \
      snk ^= (unsigned short)CUR[(2 * n_) & 7][0];                            \
      snk ^= (unsigned short)CUR[(2 * n_ + 1) & 7][0];                        \
      if (j_ + 3 <= 35) {                                                     \
        const int jn_ = j_ + 3, tr_ = jn_ >> 2, nr_ = jn_ & 3;                \
        bS[jn_ % 3] = LD8(P_ADDR_B(tr_, nr_));                                \
      }                                                                       \
    }                                                                         \
  }

#define P_CHUNK(A0, A1, NX8, KNV)                                             \
  bS[0] = LD8(P_ADDR_B(0, 0));                                                \
  bS[1] = LD8(P_ADDR_B(0, 1));                                                \
  bS[2] = LD8(P_ADDR_B(0, 2));                                                \
  P_DO_TAP(0, A0, A1, 16384, false, 0)                                        \
  P_DO_TAP(1, A1, A0, 32768, false, 0)                                        \
  P_DO_TAP(2, A0, A1, 49152, false, 0)                                        \
  P_DO_TAP(3, A1, A0, 65536, false, 0)                                        \
  P_DO_TAP(4, A0, A1, 81920, false, 0)                                        \
  P_DO_TAP(5, A1, A0, 98304, false, 0)                                        \
  P_DO_TAP(6, A0, A1, 114688, false, 0)                                       \
  P_DO_TAP(7, A1, A0, 131072, true, KNV)                                      \
  P_DO_TAP(8, A0, A1, (NX8), false, 0)                                        \
  __builtin_amdgcn_sched_barrier(0);                                          \
  asm volatile("s_waitcnt vmcnt(8)" ::: "memory");                            \
  __builtin_amdgcn_s_barrier();                                               \
  asm volatile("" ::: "memory");

  for (int rep = 0; rep < 3; ++rep) {
    const short* aGc = aG0;
#pragma unroll
    for (int i = 0; i < 6; ++i)
      gl_lds16(xS[i], wx0 + i * 4096);
#pragma unroll
    for (int m = 0; m < 8; ++m)
      aA[m] = LD8(aGc + m * 512);
    asm volatile("s_waitcnt vmcnt(0) lgkmcnt(0)" ::: "memory");
    __builtin_amdgcn_s_barrier();
    asm volatile("" ::: "memory");

    for (int c2 = 0; c2 < 8; ++c2) {
      {
        const char* qq0 = pbx[0];
        const char* qq1 = pbx[1];
        const char* qq2 = pbx[2];
        const char* qq3 = pbx3;
        char* wxw = wx0 + 24576;
        const int knv = (2 * c2 + 1) * 32;
        P_CHUNK(aA, aB, 147456, knv)
      }
      aGc += 147456;
      {
        const char* qq0 = pbx[0] + 24576;
        const char* qq1 = pbx[1] + 24576;
        const char* qq2 = pbx[2] + 24576;
        const char* qq3 = pbx3 + 24576;
        char* wxw = wx0;
        const int knv = (c2 < 7) ? (2 * c2 + 2) * 32 : 0;
        const int nx8 = (c2 < 7) ? 147456 : 0;
        P_CHUNK(aB, aA, nx8, knv)
      }
      aGc += 147456;
    }
    asm volatile("s_waitcnt vmcnt(0)" ::: "memory");
    __builtin_amdgcn_s_barrier();
  }
#undef P_CHUNK
#undef P_DO_TAP
#undef P_ADDR_B
#undef LD8

  sink[((blockIdx.x & 511) << 8) | t] = (float)snk;
}

// ---------------- fallback conv (round-1 kernel) for small ws ----------------
__global__ __launch_bounds__(256) void k_conv_fb(const float* __restrict__ x,
                                                 const short* __restrict__ Wr,
                                                 const float* __restrict__ gamma,
                                                 const float* __restrict__ dscale,
                                                 float* __restrict__ out) {
  __shared__ short As[128 * 64];
  __shared__ short Xs[4 * 64 * 64];
  __shared__ float gam_s[CIN];
  __shared__ float d_s[128];

  const int sp = blockIdx.x;
  const int ot = blockIdx.y;
  const int b  = blockIdx.z;
  const int t  = threadIdx.x;
  const int lane = t & 63;
  const int wv = t >> 6;
  const int wr = wv >> 1;
  const int wc = wv & 1;

  gam_s[t] = gamma[b * CIN + t];
  gam_s[t + 256] = gamma[b * CIN + t + 256];
  if (t < 128) d_s[t] = dscale[b * COUT + ot * 128 + t];

  f32x4 acc[4][4];
#pragma unroll
  for (int m = 0; m < 4; ++m)
#pragma unroll
    for (int n = 0; n < 4; ++n)
      acc[m][n] = (f32x4){0.f, 0.f, 0.f, 0.f};

  const int srow = t >> 6;
  const int sc = t & 63;
  const int ysrc = sp * 2 + srow - 1;
  const bool rv = (ysrc >= 0) && (ysrc < HH);
  const int ycl = rv ? ysrc : 0;
  const float* xrow = x + (((size_t)b * CIN) * HH + ycl) * WW + sc;
  short* xs_base = &Xs[(srow * 64 + sc) * 64];
  const int xs_sw = (sc & 7) << 4;

  for (int chunk = 0; chunk < CIN / 64; ++chunk) {
    const int i0 = chunk * 64;
    __syncthreads();
    {
      const float* xp = xrow + (size_t)i0 * (HH * WW);
#pragma unroll
      for (int i8 = 0; i8 < 8; ++i8) {
        short tmp[8];
#pragma unroll
        for (int j = 0; j < 8; ++j) {
          int i = i8 * 8 + j;
          float v = rv ? xp[i * (HH * WW)] : 0.0f;
          tmp[j] = f2bf(v * gam_s[i0 + i]);
        }
        char* dst = (char*)xs_base + ((i8 * 16) ^ xs_sw);
        *reinterpret_cast<bf16x8*>(dst) = *reinterpret_cast<const bf16x8*>(tmp);
      }
    }
    for (int tap = 0; tap < TAPS; ++tap) {
      __syncthreads();
#pragma unroll
      for (int j = 0; j < 4; ++j) {
        int s = t + 256 * j;
        int row = s >> 3, sl = s & 7;
        int kbyte = (sl * 16) ^ ((row & 7) << 4);
        const short* src = Wr + ((size_t)(ot * 128 + row) * TAPS + tap) * CIN +
                           i0 + (kbyte >> 1);
        *reinterpret_cast<bf16x8*>((char*)As + row * 128 + sl * 16) =
            *reinterpret_cast<const bf16x8*>(src);
      }
      __syncthreads();

      const int dy = tap / 3 - 1, dx = tap % 3 - 1;
      bf16x8 afr[2][4], bfr[2][4];
#pragma unroll
      for (int kk = 0; kk < 2; ++kk) {
        const int kb = kk * 64 + (lane >> 4) * 16;
#pragma unroll
        for (int m = 0; m < 4; ++m) {
          int row = wr * 64 + m * 16 + (lane & 15);
          afr[kk][m] = *reinterpret_cast<const bf16x8*>(
              (const char*)As + row * 128 + (kb ^ ((row & 7) << 4)));
        }
#pragma unroll
        for (int n = 0; n < 4; ++n) {
          int p = wc * 64 + n * 16 + (lane & 15);
          int r = p >> 6, c = p & 63;
          int cc = c + dx;
          bool val = (cc >= 0) && (cc < WW);
          int ccl = val ? cc : 0;
          int rr = r + dy + 1;
          bf16x8 f = *reinterpret_cast<const bf16x8*>(
              (const char*)Xs + (rr * 64 + ccl) * 128 + (kb ^ ((ccl & 7) << 4)));
          if (!val) f = (bf16x8){0, 0, 0, 0, 0, 0, 0, 0};
          bfr[kk][n] = f;
        }
      }
#pragma unroll
      for (int m = 0; m < 4; ++m)
#pragma unroll
        for (int n = 0; n < 4; ++n)
#pragma unroll
          for (int kk = 0; kk < 2; ++kk)
            acc[m][n] = __builtin_amdgcn_mfma_f32_16x16x32_bf16(
                afr[kk][m], bfr[kk][n], acc[m][n], 0, 0, 0);
    }
  }

#pragma unroll
  for (int m = 0; m < 4; ++m) {
#pragma unroll
    for (int n = 0; n < 4; ++n) {
#pragma unroll
      for (int j = 0; j < 4; ++j) {
        int o_l = wr * 64 + m * 16 + (lane >> 4) * 4 + j;
        int o = ot * 128 + o_l;
        int p = wc * 64 + n * 16 + (lane & 15);
        int yy = sp * 2 + (p >> 6);
        int cx = p & 63;
        out[(((size_t)b * COUT + o) * HH + yy) * WW + cx] = d_s[o_l] * acc[m][n][j];
      }
    }
  }
}

extern "C" void kernel_launch(void* const* d_in, const int* in_sizes, int n_in,
                              void* d_out, int out_size, void* d_ws, size_t ws_size,
                              hipStream_t stream) {
  const float* x = (const float*)d_in[0];
  const float* y = (const float*)d_in[1];
  const float* w_conv = (const float*)d_in[2];
  const float* w_gamma = (const float*)d_in[3];
  const float* b_gamma = (const float*)d_in[4];
  float* out = (float*)d_out;

  char* ws = (char*)d_ws;
  short* W2 = (short*)ws;                        // 4,718,592 B (+pad)
  float* gamma = (float*)(ws + 4849664);         // 32,768 B
  float* dsc = (float*)(ws + 4882432);           // 32,768 B
  float* s2 = (float*)(ws + 4915200);            // 1,048,576 B (probe sinks after k_d3)
  char* zbuf = ws + 5963776;                     // 4,096 B zero page
  short* xm = (short*)(ws + 5967872);            // 67,108,864 B
  const size_t NEED = 5967872 + (size_t)NB * HH * WW * CIN * 2 + 4096;

  const bool fast = ws_size >= NEED;

  if (fast) {
    hipLaunchKernelGGL(k_pg, dim3(512 + NB), dim3(512), 0, stream, w_conv, y,
                       w_gamma, b_gamma, s2, W2, gamma, (float*)zbuf);
    hipLaunchKernelGGL(k_d3, dim3(128), dim3(512), 0, stream, gamma, s2, dsc);
    hipLaunchKernelGGL(k_xmod2, dim3(HH, NB), dim3(256), 0, stream, x, gamma, xm);
    hipLaunchKernelGGL(k_conv13, dim3(1024), dim3(256), 0, stream, xm, W2,
                       (const short*)zbuf, dsc, out);
    // ---- timing probes (write only to dead s2 scratch; out untouched) ----
    hipLaunchKernelGGL(k_probeM, dim3(2048), dim3(256), 0, stream, dsc, s2);
    hipLaunchKernelGGL(k_probeL, dim3(1024), dim3(256), 0, stream, xm, W2,
                       (const short*)zbuf, dsc, s2 + 131072);
  } else {
    hipLaunchKernelGGL(k_gamma, dim3(NB), dim3(512), 0, stream, y, w_gamma,
                       b_gamma, gamma, (float*)nullptr);
    hipLaunchKernelGGL(k_prep, dim3(COUT), dim3(256), 0, stream, w_conv, s2, W2);
    hipLaunchKernelGGL(k_d, dim3(NB), dim3(512), 0, stream, gamma, s2, dsc);
    hipLaunchKernelGGL(k_conv_fb, dim3(32, 4, NB), dim3(256), 0, stream, x, W2,
                       gamma, dsc, out);
  }
}

// Round 17
// 306.361 us; speedup vs baseline: 5.2774x; 5.2774x over previous
//
#include <hip/hip_runtime.h>
#include <stdint.h>

#define NB   16
#define CIN  512
#define COUT 512
#define HH   64
#define WW   64
#define NCOND 512
#define TAPS 9
#define EPSD 1e-8f

typedef short bf16x8 __attribute__((ext_vector_type(8)));
typedef float f32x4 __attribute__((ext_vector_type(4)));

static __device__ __forceinline__ short f2bf(float f) {
  union { float f; uint32_t u; } c;
  c.f = f;
  uint32_t u = c.u;
  uint32_t r = (u + 0x7FFFu + ((u >> 16) & 1u)) >> 16;
  return (short)(uint16_t)r;
}

static __device__ __forceinline__ void gl_lds16(const void* g, void* l) {
  __builtin_amdgcn_global_load_lds(
      (const __attribute__((address_space(1))) void*)g,
      (__attribute__((address_space(3))) void*)l, 16, 0, 0);
}

// ---- k_pg: fused {prep2 (blocks 0..511)} + {gamma (blocks 512..527)} --------
__global__ __launch_bounds__(512) void k_pg(const float* __restrict__ w_conv,
                                            const float* __restrict__ y,
                                            const float* __restrict__ w_gamma,
                                            const float* __restrict__ b_gamma,
                                            float* __restrict__ s2,
                                            short* __restrict__ W2,
                                            float* __restrict__ gamma,
                                            float* __restrict__ zbuf) {
  __shared__ float ws_s[CIN * TAPS];
  const int t = threadIdx.x;
  if (blockIdx.x < 512) {
    const int o = blockIdx.x;
    const float* wsrc = w_conv + (size_t)o * CIN * TAPS;
    for (int idx = t; idx < CIN * TAPS; idx += 512) ws_s[idx] = wsrc[idx];
    __syncthreads();
    {
      int i = t;
      float s = 0.f;
#pragma unroll
      for (int tap = 0; tap < TAPS; ++tap) {
        float v = ws_s[i * TAPS + tap];
        s += v * v;
      }
      s2[(size_t)o * CIN + i] = s;
    }
    const int key = (o >> 1) & 3;
    for (int k = t; k < CIN * TAPS; k += 512) {
      int tap = k >> 9;
      int r = k & 511;
      int c = r >> 5, sl = (r >> 3) & 3, j = r & 7;
      W2[((size_t)(c * TAPS + tap) * COUT + o) * 32 + ((sl ^ key) * 8) + j] =
          f2bf(ws_s[r * TAPS + tap]);
    }
  } else {
    const int b = blockIdx.x - 512;
    if (b == 0) { zbuf[t] = 0.f; zbuf[t + 512] = 0.f; }  // 4KB zeros
    ws_s[t] = y[b * NCOND + t];
    __syncthreads();
    const float4* wg = reinterpret_cast<const float4*>(w_gamma + (size_t)t * NCOND);
    float acc = b_gamma[t];
    for (int c4 = 0; c4 < NCOND / 4; ++c4) {
      float4 w4 = wg[c4];
      acc += w4.x * ws_s[c4 * 4 + 0] + w4.y * ws_s[c4 * 4 + 1] +
             w4.z * ws_s[c4 * 4 + 2] + w4.w * ws_s[c4 * 4 + 3];
    }
    gamma[b * CIN + t] = acc;
  }
}

// ---------------- k_d3: parallel demod scale (grid 128) ----------------------
__global__ __launch_bounds__(512) void k_d3(const float* __restrict__ gamma,
                                            const float* __restrict__ s2,
                                            float* __restrict__ dscale) {
  __shared__ float g2[CIN];
  __shared__ float red[512];
  const int b = blockIdx.x >> 3;
  const int og = blockIdx.x & 7;
  const int t = threadIdx.x;
  float g = gamma[b * CIN + t];
  g2[t] = g * g;
  __syncthreads();
  const int o_l = t >> 3, seg = t & 7;
  const int o = og * 64 + o_l;
  const float4* s4 = reinterpret_cast<const float4*>(s2 + (size_t)o * CIN + seg * 64);
  float p = 0.f;
#pragma unroll
  for (int c4 = 0; c4 < 16; ++c4) {
    float4 v = s4[c4];
    int base = seg * 64 + c4 * 4;
    p += v.x * g2[base + 0] + v.y * g2[base + 1] +
         v.z * g2[base + 2] + v.w * g2[base + 3];
  }
  red[t] = p;
  __syncthreads();
  if (seg == 0) {
    float s = 0.f;
#pragma unroll
    for (int k = 0; k < 8; ++k) s += red[o_l * 8 + k];
    dscale[b * COUT + o] = rsqrtf(s + EPSD);
  }
}

// ---------------- fallback prelude kernels -----------------------------------
__global__ __launch_bounds__(512) void k_gamma(const float* __restrict__ y,
                                               const float* __restrict__ w_gamma,
                                               const float* __restrict__ b_gamma,
                                               float* __restrict__ gamma,
                                               float* __restrict__ zbuf) {
  __shared__ float ys[NCOND];
  const int b = blockIdx.x;
  const int i = threadIdx.x;
  if (zbuf && b == 0) { zbuf[i] = 0.f; zbuf[i + 512] = 0.f; }
  ys[i] = y[b * NCOND + i];
  __syncthreads();
  const float4* wg = reinterpret_cast<const float4*>(w_gamma + (size_t)i * NCOND);
  float acc = b_gamma[i];
  for (int c4 = 0; c4 < NCOND / 4; ++c4) {
    float4 w4 = wg[c4];
    acc += w4.x * ys[c4 * 4 + 0] + w4.y * ys[c4 * 4 + 1] +
           w4.z * ys[c4 * 4 + 2] + w4.w * ys[c4 * 4 + 3];
  }
  gamma[b * CIN + i] = acc;
}

__global__ __launch_bounds__(256) void k_prep(const float* __restrict__ w_conv,
                                              float* __restrict__ s2,
                                              short* __restrict__ Wr) {
  __shared__ float ws_s[CIN * TAPS];
  const int o = blockIdx.x;
  const int t = threadIdx.x;
  const float* wsrc = w_conv + (size_t)o * CIN * TAPS;
  for (int idx = t; idx < CIN * TAPS; idx += 256) ws_s[idx] = wsrc[idx];
  __syncthreads();
  for (int i = t; i < CIN; i += 256) {
    float s = 0.f;
#pragma unroll
    for (int tap = 0; tap < TAPS; ++tap) {
      float v = ws_s[i * TAPS + tap];
      s += v * v;
    }
    s2[(size_t)o * CIN + i] = s;
  }
  for (int idx = t; idx < CIN * TAPS; idx += 256) {
    int i = idx & (CIN - 1);
    int tap = idx >> 9;
    Wr[((size_t)o * TAPS + tap) * CIN + i] = f2bf(ws_s[i * TAPS + tap]);
  }
}

__global__ __launch_bounds__(512) void k_d(const float* __restrict__ gamma,
                                           const float* __restrict__ s2,
                                           float* __restrict__ dscale) {
  __shared__ float g2[CIN];
  const int b = blockIdx.x;
  const int o = threadIdx.x;
  float g = gamma[b * CIN + o];
  g2[o] = g * g;
  __syncthreads();
  const float4* s4 = reinterpret_cast<const float4*>(s2 + (size_t)o * CIN);
  float acc = 0.f;
  for (int i4 = 0; i4 < CIN / 4; ++i4) {
    float4 v = s4[i4];
    acc += v.x * g2[i4 * 4 + 0] + v.y * g2[i4 * 4 + 1] +
           v.z * g2[i4 * 4 + 2] + v.w * g2[i4 * 4 + 3];
  }
  dscale[b * COUT + o] = rsqrtf(acc + EPSD);
}

// -- k_xmod2: xm[b][y][w][cin] bf16 modulated, 16B-slot pre-swizzled by w -----
__global__ __launch_bounds__(256) void k_xmod2(const float* __restrict__ x,
                                               const float* __restrict__ gamma,
                                               short* __restrict__ xm) {
  __shared__ float tile[64][67];
  __shared__ float gs[CIN];
  const int y = blockIdx.x, b = blockIdx.y;
  const int t = threadIdx.x;
  gs[t] = gamma[b * CIN + t];
  gs[t + 256] = gamma[b * CIN + t + 256];
  __syncthreads();
  const int w = t >> 2, q = t & 3;
  const int sw = (w >> 1) & 3;
  short* dst = xm + (((size_t)b * HH + y) * WW + w) * CIN;
  for (int c0 = 0; c0 < CIN; c0 += 64) {
    {
      int ww_ = t & 63;
      int cb = t >> 6;
      const float* xp = x + (((size_t)(b * CIN + c0 + cb)) * HH + y) * WW + ww_;
#pragma unroll
      for (int p = 0; p < 16; ++p)
        tile[cb + p * 4][ww_] = xp[(size_t)p * 4 * HH * WW];
    }
    __syncthreads();
#pragma unroll
    for (int h = 0; h < 2; ++h) {
      int c_lo = q * 16 + h * 8;
      int chunk = (c0 + c_lo) >> 5;
      int sl = (c_lo >> 3) & 3;
      short tmp[8];
#pragma unroll
      for (int j = 0; j < 8; ++j)
        tmp[j] = f2bf(tile[c_lo + j][w] * gs[c0 + c_lo + j]);
      *reinterpret_cast<bf16x8*>(dst + chunk * 32 + (sl ^ sw) * 8) =
          *reinterpret_cast<const bf16x8*>(tmp);
    }
    __syncthreads();
  }
}

// ---------------- k_conv13 (best-known, verified): B-pipelined conv ----------
// grid 1024, 256 thr = 4 waves. Block tile 128 cout x 256 px; wave 128x64.
// A global->VGPR dbuf 1 tap ahead; X LDS dbuf. B-frag reads pipelined depth-2.
// Plateau note: 249us @ MfmaUtil 57% — 2 waves/SIMD GPR ceiling (128 VGPR +
// 128 AGPR acc); MFMA-only probe of this cluster shape ran at ~ubench rate,
// so the residual gap is per-wave wait interleave, invariant across 7
// schedule variants tried (R6-R15).
__global__ __launch_bounds__(256, 2) void k_conv13(const short* __restrict__ xm,
                                                   const short* __restrict__ W2,
                                                   const short* __restrict__ zbuf,
                                                   const float* __restrict__ dscale,
                                                   float* __restrict__ out) {
  __shared__ short Xs[2 * 6 * 64 * 32];
  __shared__ float d_s[128];
  __shared__ __align__(16) short zls[64];

  const int orig = blockIdx.x;
  const int wgid = ((orig & 7) << 7) | (orig >> 3);
  const int ot = wgid >> 8;
  const int b  = (wgid >> 4) & 15;
  const int sp = wgid & 15;

  const int t = threadIdx.x, lane = t & 63;
  const int wc = t >> 6;
  const int l15 = lane & 15;
  const int slA = lane >> 4;

  if (t < 128) d_s[t] = dscale[b * COUT + ot * 128 + t];
  if (t < 64) zls[t] = 0;

  const short* xS[6];
#pragma unroll
  for (int i = 0; i < 6; ++i) {
    int idx = t + 256 * i;
    int rb = idx >> 8;
    int w = (idx & 255) >> 2;
    int sl = idx & 3;
    int ysrc = sp * 4 + rb - 1;
    bool rv = (ysrc >= 0) && (ysrc < HH);
    xS[i] = rv ? xm + (((size_t)b * HH + ysrc) * WW + w) * CIN + sl * 8
               : zbuf + sl * 8;
  }

  const int o0 = ot * 128 + l15;
  const int keyA = (o0 >> 1) & 3;
  const short* aGc = W2 + (size_t)o0 * 32 + ((slA ^ keyA) * 8);

  const int kb0 = slA << 4;
  const char* pbx[3];
#pragma unroll
  for (int dxi = 0; dxi < 3; ++dxi) {
    int lcc = l15 + dxi - 1;
    int key = (lcc >> 1) & 3;
    pbx[dxi] = (const char*)&Xs[0] + lcc * 64 + (kb0 ^ (key << 4));
  }
  const int lc3 = (l15 + 1 > 15) ? 15 : (l15 + 1);
  const char* pbx3 = (const char*)&Xs[0] + lc3 * 64 + (kb0 ^ (((lc3 >> 1) & 3) << 4));
  char* wx0 = (char*)&Xs[0] + t * 16;
  const char* zl = (const char*)&zls[0];
  const bool mL = (l15 == 0);
  const bool mR = (l15 == 15);

  f32x4 acc[8][4];
#pragma unroll
  for (int m = 0; m < 8; ++m)
#pragma unroll
    for (int n = 0; n < 4; ++n)
      acc[m][n] = (f32x4){0.f, 0.f, 0.f, 0.f};

  bf16x8 aA[8], aB[8];
  bf16x8 bS[3];

#pragma unroll
  for (int i = 0; i < 6; ++i)
    gl_lds16(xS[i], wx0 + i * 4096);
#pragma unroll
  for (int m = 0; m < 8; ++m)
    aA[m] = *reinterpret_cast<const bf16x8*>(aGc + m * 512);
  asm volatile("s_waitcnt vmcnt(0) lgkmcnt(0)" ::: "memory");
  __builtin_amdgcn_s_barrier();
  asm volatile("" ::: "memory");

#define LD8(p) (*reinterpret_cast<const bf16x8*>(p))

#define ADDR_B(tq_, nq_)                                                      \
  ({ const int dyz_ = (tq_) / 3 - 1, dxz_ = (tq_) % 3 - 1;                    \
     const int rboz_ = (wc + dyz_ + 1) * 4096;                                \
     const char* pz_;                                                         \
     if (dxz_ == -1 && (nq_) == 0) pz_ = mL ? (zl - rboz_) : qq0;             \
     else if (dxz_ == 1 && (nq_) == 3) pz_ = mR ? (zl - rboz_ - 3072) : qq3;  \
     else pz_ = (dxz_ == -1) ? qq0 : ((dxz_ == 0) ? qq1 : qq2);               \
     pz_ + rboz_ + (nq_) * 1024; })

#define DO_TAP(tp, CUR, NXT, NXTOFF, STGX, KNV)                               \
  {                                                                           \
    const short* an_ = aGc + (NXTOFF);                                        \
    _Pragma("unroll") for (int m_ = 0; m_ < 8; ++m_)                          \
        NXT[m_] = LD8(an_ + m_ * 512);                                        \
    if (STGX) {                                                               \
      _Pragma("unroll") for (int i_ = 0; i_ < 6; ++i_)                        \
          gl_lds16(xS[i_] + (KNV), wxw + i_ * 4096);                          \
    }                                                                         \
    _Pragma("unroll") for (int n_ = 0; n_ < 4; ++n_) {                        \
      const int j_ = (tp) * 4 + n_;                                           \
      if (j_ <= 33) { asm volatile("s_waitcnt lgkmcnt(2)" ::: "memory"); }    \
      else if (j_ == 34) { asm volatile("s_waitcnt lgkmcnt(1)" ::: "memory"); } \
      else { asm volatile("s_waitcnt lgkmcnt(0)" ::: "memory"); }             \
      __builtin_amdgcn_sched_barrier(0);                                      \
      __builtin_amdgcn_s_setprio(1);                                          \
      _Pragma("unroll") for (int m_ = 0; m_ < 8; ++m_)                        \
        acc[m_][n_] = __builtin_amdgcn_mfma_f32_16x16x32_bf16(                \
            CUR[m_], bS[j_ % 3], acc[m_][n_], 0, 0, 0);                       \
      __builtin_amdgcn_s_setprio(0);                                          \
      if (j_ + 3 <= 35) {                                                     \
        const int jn_ = j_ + 3, tr_ = jn_ >> 2, nr_ = jn_ & 3;                \
        bS[jn_ % 3] = LD8(ADDR_B(tr_, nr_));                                  \
      }                                                                       \
    }                                                                         \
  }

#define CHUNK_TAPS(A0, A1, NX8, KNV)                                          \
  bS[0] = LD8(ADDR_B(0, 0));                                                  \
  bS[1] = LD8(ADDR_B(0, 1));                                                  \
  bS[2] = LD8(ADDR_B(0, 2));                                                  \
  DO_TAP(0, A0, A1, 16384, false, 0)                                          \
  DO_TAP(1, A1, A0, 32768, false, 0)                                          \
  DO_TAP(2, A0, A1, 49152, false, 0)                                          \
  DO_TAP(3, A1, A0, 65536, false, 0)                                          \
  DO_TAP(4, A0, A1, 81920, false, 0)                                          \
  DO_TAP(5, A1, A0, 98304, false, 0)                                          \
  DO_TAP(6, A0, A1, 114688, false, 0)                                         \
  DO_TAP(7, A1, A0, 131072, true, KNV)                                        \
  DO_TAP(8, A0, A1, (NX8), false, 0)                                          \
  __builtin_amdgcn_sched_barrier(0);                                          \
  asm volatile("s_waitcnt vmcnt(8)" ::: "memory");                            \
  __builtin_amdgcn_s_barrier();                                               \
  asm volatile("" ::: "memory");

  for (int c2 = 0; c2 < 8; ++c2) {
    {
      const char* qq0 = pbx[0];
      const char* qq1 = pbx[1];
      const char* qq2 = pbx[2];
      const char* qq3 = pbx3;
      char* wxw = wx0 + 24576;
      const int knv = (2 * c2 + 1) * 32;
      CHUNK_TAPS(aA, aB, 147456, knv)
    }
    aGc += 147456;
    {
      const char* qq0 = pbx[0] + 24576;
      const char* qq1 = pbx[1] + 24576;
      const char* qq2 = pbx[2] + 24576;
      const char* qq3 = pbx3 + 24576;
      char* wxw = wx0;
      const int knv = (c2 < 7) ? (2 * c2 + 2) * 32 : 0;
      const int nx8 = (c2 < 7) ? 147456 : 0;
      CHUNK_TAPS(aB, aA, nx8, knv)
    }
    aGc += 147456;
  }
#undef CHUNK_TAPS
#undef DO_TAP
#undef ADDR_B
#undef LD8

#pragma unroll
  for (int m = 0; m < 8; ++m) {
#pragma unroll
    for (int n = 0; n < 4; ++n) {
#pragma unroll
      for (int j = 0; j < 4; ++j) {
        int o_l = m * 16 + (lane >> 4) * 4 + j;
        int o = ot * 128 + o_l;
        int yy = sp * 4 + wc;
        int cx = n * 16 + l15;
        out[(((size_t)b * COUT + o) * HH + yy) * WW + cx] = d_s[o_l] * acc[m][n][j];
      }
    }
  }
}

// ---------------- fallback conv (round-1 kernel) for small ws ----------------
__global__ __launch_bounds__(256) void k_conv_fb(const float* __restrict__ x,
                                                 const short* __restrict__ Wr,
                                                 const float* __restrict__ gamma,
                                                 const float* __restrict__ dscale,
                                                 float* __restrict__ out) {
  __shared__ short As[128 * 64];
  __shared__ short Xs[4 * 64 * 64];
  __shared__ float gam_s[CIN];
  __shared__ float d_s[128];

  const int sp = blockIdx.x;
  const int ot = blockIdx.y;
  const int b  = blockIdx.z;
  const int t  = threadIdx.x;
  const int lane = t & 63;
  const int wv = t >> 6;
  const int wr = wv >> 1;
  const int wc = wv & 1;

  gam_s[t] = gamma[b * CIN + t];
  gam_s[t + 256] = gamma[b * CIN + t + 256];
  if (t < 128) d_s[t] = dscale[b * COUT + ot * 128 + t];

  f32x4 acc[4][4];
#pragma unroll
  for (int m = 0; m < 4; ++m)
#pragma unroll
    for (int n = 0; n < 4; ++n)
      acc[m][n] = (f32x4){0.f, 0.f, 0.f, 0.f};

  const int srow = t >> 6;
  const int sc = t & 63;
  const int ysrc = sp * 2 + srow - 1;
  const bool rv = (ysrc >= 0) && (ysrc < HH);
  const int ycl = rv ? ysrc : 0;
  const float* xrow = x + (((size_t)b * CIN) * HH + ycl) * WW + sc;
  short* xs_base = &Xs[(srow * 64 + sc) * 64];
  const int xs_sw = (sc & 7) << 4;

  for (int chunk = 0; chunk < CIN / 64; ++chunk) {
    const int i0 = chunk * 64;
    __syncthreads();
    {
      const float* xp = xrow + (size_t)i0 * (HH * WW);
#pragma unroll
      for (int i8 = 0; i8 < 8; ++i8) {
        short tmp[8];
#pragma unroll
        for (int j = 0; j < 8; ++j) {
          int i = i8 * 8 + j;
          float v = rv ? xp[i * (HH * WW)] : 0.0f;
          tmp[j] = f2bf(v * gam_s[i0 + i]);
        }
        char* dst = (char*)xs_base + ((i8 * 16) ^ xs_sw);
        *reinterpret_cast<bf16x8*>(dst) = *reinterpret_cast<const bf16x8*>(tmp);
      }
    }
    for (int tap = 0; tap < TAPS; ++tap) {
      __syncthreads();
#pragma unroll
      for (int j = 0; j < 4; ++j) {
        int s = t + 256 * j;
        int row = s >> 3, sl = s & 7;
        int kbyte = (sl * 16) ^ ((row & 7) << 4);
        const short* src = Wr + ((size_t)(ot * 128 + row) * TAPS + tap) * CIN +
                           i0 + (kbyte >> 1);
        *reinterpret_cast<bf16x8*>((char*)As + row * 128 + sl * 16) =
            *reinterpret_cast<const bf16x8*>(src);
      }
      __syncthreads();

      const int dy = tap / 3 - 1, dx = tap % 3 - 1;
      bf16x8 afr[2][4], bfr[2][4];
#pragma unroll
      for (int kk = 0; kk < 2; ++kk) {
        const int kb = kk * 64 + (lane >> 4) * 16;
#pragma unroll
        for (int m = 0; m < 4; ++m) {
          int row = wr * 64 + m * 16 + (lane & 15);
          afr[kk][m] = *reinterpret_cast<const bf16x8*>(
              (const char*)As + row * 128 + (kb ^ ((row & 7) << 4)));
        }
#pragma unroll
        for (int n = 0; n < 4; ++n) {
          int p = wc * 64 + n * 16 + (lane & 15);
          int r = p >> 6, c = p & 63;
          int cc = c + dx;
          bool val = (cc >= 0) && (cc < WW);
          int ccl = val ? cc : 0;
          int rr = r + dy + 1;
          bf16x8 f = *reinterpret_cast<const bf16x8*>(
              (const char*)Xs + (rr * 64 + ccl) * 128 + (kb ^ ((ccl & 7) << 4)));
          if (!val) f = (bf16x8){0, 0, 0, 0, 0, 0, 0, 0};
          bfr[kk][n] = f;
        }
      }
#pragma unroll
      for (int m = 0; m < 4; ++m)
#pragma unroll
        for (int n = 0; n < 4; ++n)
#pragma unroll
          for (int kk = 0; kk < 2; ++kk)
            acc[m][n] = __builtin_amdgcn_mfma_f32_16x16x32_bf16(
                afr[kk][m], bfr[kk][n], acc[m][n], 0, 0, 0);
    }
  }

#pragma unroll
  for (int m = 0; m < 4; ++m) {
#pragma unroll
    for (int n = 0; n < 4; ++n) {
#pragma unroll
      for (int j = 0; j < 4; ++j) {
        int o_l = wr * 64 + m * 16 + (lane >> 4) * 4 + j;
        int o = ot * 128 + o_l;
        int p = wc * 64 + n * 16 + (lane & 15);
        int yy = sp * 2 + (p >> 6);
        int cx = p & 63;
        out[(((size_t)b * COUT + o) * HH + yy) * WW + cx] = d_s[o_l] * acc[m][n][j];
      }
    }
  }
}

extern "C" void kernel_launch(void* const* d_in, const int* in_sizes, int n_in,
                              void* d_out, int out_size, void* d_ws, size_t ws_size,
                              hipStream_t stream) {
  const float* x = (const float*)d_in[0];
  const float* y = (const float*)d_in[1];
  const float* w_conv = (const float*)d_in[2];
  const float* w_gamma = (const float*)d_in[3];
  const float* b_gamma = (const float*)d_in[4];
  float* out = (float*)d_out;

  char* ws = (char*)d_ws;
  short* W2 = (short*)ws;                        // 4,718,592 B (+pad)
  float* gamma = (float*)(ws + 4849664);         // 32,768 B
  float* dsc = (float*)(ws + 4882432);           // 32,768 B
  float* s2 = (float*)(ws + 4915200);            // 1,048,576 B
  char* zbuf = ws + 5963776;                     // 4,096 B zero page
  short* xm = (short*)(ws + 5967872);            // 67,108,864 B
  const size_t NEED = 5967872 + (size_t)NB * HH * WW * CIN * 2 + 4096;

  const bool fast = ws_size >= NEED;

  if (fast) {
    hipLaunchKernelGGL(k_pg, dim3(512 + NB), dim3(512), 0, stream, w_conv, y,
                       w_gamma, b_gamma, s2, W2, gamma, (float*)zbuf);
    hipLaunchKernelGGL(k_d3, dim3(128), dim3(512), 0, stream, gamma, s2, dsc);
    hipLaunchKernelGGL(k_xmod2, dim3(HH, NB), dim3(256), 0, stream, x, gamma, xm);
    hipLaunchKernelGGL(k_conv13, dim3(1024), dim3(256), 0, stream, xm, W2,
                       (const short*)zbuf, dsc, out);
  } else {
    hipLaunchKernelGGL(k_gamma, dim3(NB), dim3(512), 0, stream, y, w_gamma,
                       b_gamma, gamma, (float*)nullptr);
    hipLaunchKernelGGL(k_prep, dim3(COUT), dim3(256), 0, stream, w_conv, s2, W2);
    hipLaunchKernelGGL(k_d, dim3(NB), dim3(512), 0, stream, gamma, s2, dsc);
    hipLaunchKernelGGL(k_conv_fb, dim3(32, 4, NB), dim3(256), 0, stream, x, W2,
                       gamma, dsc, out);
  }
}